// Round 9
// baseline (7979.344 us; speedup 1.0000x reference)
//
#include <hip/hip_runtime.h>

#define TW    10000
#define EMBD  100
#define SEQ   80
#define U     512
#define BATCH 2048
#define RPB   16
#define NBLK  (BATCH / RPB)   // 128 blocks
#define NTHR  1024            // 16 waves/block

typedef short short8 __attribute__((ext_vector_type(8)));
typedef float f32x4 __attribute__((ext_vector_type(4)));

static __device__ __forceinline__ unsigned short f2bf(float f){
  unsigned int u = __float_as_uint(f);
  u += 0x7fffu + ((u >> 16) & 1u);   // RNE
  return (unsigned short)(u >> 16);
}
static __device__ __forceinline__ float bf2f(unsigned short h){
  return __uint_as_float(((unsigned int)h) << 16);
}
static __device__ __forceinline__ float fast_tanh(float x){
  float e = __expf(2.0f * x);        // inf-safe: saturates to +-1
  return 1.0f - 2.0f / (e + 1.0f);
}

// ---------------- proj[w][n] = b0[n] + sum_e emb[w][e] * Wx0[e][n] ----------------
__global__ void proj_kernel(const float* __restrict__ emb, const float* __restrict__ Wx0,
                            const float* __restrict__ b0, float* __restrict__ proj){
  __shared__ float es[16][EMBD];
  const int w0 = blockIdx.x * 16;
  for (int i = threadIdx.x; i < 16 * EMBD; i += 256)
    es[i / EMBD][i % EMBD] = emb[(size_t)w0 * EMBD + i];
  __syncthreads();
  const int n = threadIdx.x;   // cols n and n+256
  float accA[16], accB[16];
#pragma unroll
  for (int wi = 0; wi < 16; ++wi){ accA[wi] = 0.0f; accB[wi] = 0.0f; }
  for (int e = 0; e < EMBD; ++e){
    const float wv0 = Wx0[(size_t)e * U + n];
    const float wv1 = Wx0[(size_t)e * U + n + 256];
#pragma unroll
    for (int wi = 0; wi < 16; ++wi){
      accA[wi] += es[wi][e] * wv0;
      accB[wi] += es[wi][e] * wv1;
    }
  }
  const float bb0 = b0[n], bb1 = b0[n + 256];
  for (int wi = 0; wi < 16; ++wi){
    proj[(size_t)(w0 + wi) * U + n]       = accA[wi] + bb0;
    proj[(size_t)(w0 + wi) * U + n + 256] = accB[wi] + bb1;
  }
}

// ---------------- dst[n][kOff + k] = bf16(src[k][n]),  src is [K][N] f32 ----------------
__global__ void transpose_bf16(const float* __restrict__ src, unsigned short* __restrict__ dst,
                               int K, int N, int dstLd, int kOff){
  const int idx = blockIdx.x * 256 + threadIdx.x;
  if (idx >= K * N) return;
  const int k = idx % K, n = idx / K;
  dst[(size_t)n * dstLd + kOff + k] = f2bf(src[(size_t)k * N + n]);
}

// One 512-K segment (16 chunks of 32 k): B flows global->VGPR->LDS ring->MFMA.
// Chunk c lives in reg-set c%2 (loaded iter c-2), LDS slot c%3 (written iter c-1,
// read iter c). Private per-wave ring -> no barriers; same-wave DS ops are
// in-order. Loads are REGULAR (L3-backstopped; nt/gload_lds bypass L3 - R2/R7).
static __device__ __forceinline__ void seg16(
    const unsigned short* __restrict__ W,
    unsigned g0, unsigned g1,            // per-lane global elem offsets, chunk 0, col-tiles 0/1
    unsigned short* ring,                // this wave's 3 x 1024-elem ring
    unsigned wo0, unsigned wo1,          // in-slot write elem offsets (swizzled)
    unsigned ro0, unsigned ro1,          // in-slot read  elem offsets (swizzled)
    const unsigned short* __restrict__ stA,
    int aBase, int aSwz, f32x4* acc)
{
  short8 e0, e1, o0, o1;
#define GLD0 { e0 = *reinterpret_cast<const short8*>(W + g0 + 0u);        \
               e1 = *reinterpret_cast<const short8*>(W + g1 + 0u); }
#define GLD(set0, set1, c) { set0 = *reinterpret_cast<const short8*>(W + g0 + (unsigned)((c) * 32)); \
                             set1 = *reinterpret_cast<const short8*>(W + g1 + (unsigned)((c) * 32)); }
#define SWR(slot, v0, v1) { unsigned short* sl_ = ring + (slot) * 1024;   \
    *reinterpret_cast<short8*>(sl_ + wo0) = v0;                           \
    *reinterpret_cast<short8*>(sl_ + wo1) = v1; }

  GLD(e0, e1, 0)
  GLD(o0, o1, 1)
  SWR(0, e0, e1)
#pragma unroll
  for (int r = 0; r < 16; ++r){
    if (r + 2 < 16){                       // load chunk r+2 into set (r+2)%2 == r%2
      if ((r & 1) == 0) GLD(e0, e1, r + 2)
      else              GLD(o0, o1, r + 2)
    }
    if (r + 1 < 16){                       // write chunk r+1 (set (r+1)%2) to slot (r+1)%3
      if (((r + 1) & 1) == 0) SWR((r + 1) % 3, e0, e1)
      else                    SWR((r + 1) % 3, o0, o1)
    }
    // compute chunk r from slot r%3
    const unsigned short* sl = ring + (r % 3) * 1024;
    short8 a  = *reinterpret_cast<const short8*>(&stA[(aBase + r * 32) ^ aSwz]);
    short8 b0 = *reinterpret_cast<const short8*>(sl + ro0);
    short8 b1 = *reinterpret_cast<const short8*>(sl + ro1);
    acc[0] = __builtin_amdgcn_mfma_f32_16x16x32_bf16(a, b0, acc[0], 0, 0, 0);
    acc[1] = __builtin_amdgcn_mfma_f32_16x16x32_bf16(a, b1, acc[1], 0, 0, 0);
  }
#undef GLD0
#undef GLD
#undef SWR
}

// ---------------- persistent per-block RNN: 16 rows through all 80 steps ----------------
__global__ __launch_bounds__(NTHR, 4)
void rnn_persist(const int* __restrict__ tokens,
                 const float* __restrict__ proj,
                 const unsigned short* __restrict__ Wh0t,
                 const unsigned short* __restrict__ W1t,
                 const unsigned short* __restrict__ W2t,
                 const float* __restrict__ b1,
                 const float* __restrict__ b2,
                 const float* __restrict__ Wout,
                 const float* __restrict__ bout,
                 float* __restrict__ out)
{
  extern __shared__ unsigned short smem[];
  unsigned short* st0 = smem;              // 16 KiB (16 x 512, XOR-swizzled rows)
  unsigned short* st1 = smem + 8192;       // 16 KiB
  unsigned short* st2 = smem + 16384;      // 16 KiB
  unsigned short* ringAll = smem + 24576;  // 96 KiB: 16 waves x 3 slots x 1024 elems

  const int tid = threadIdx.x;
  for (int i = tid; i < 3 * 8192; i += NTHR) smem[i] = 0;
  __syncthreads();

  const int lane = tid & 63;
  const int wid  = tid >> 6;          // 16 waves, 32 output cols each
  const int l15  = lane & 15;
  const int khi  = lane >> 4;         // 0..3
  const int n0   = wid * 32;
  const int rowbase = blockIdx.x * RPB;

  unsigned short* ring = ringAll + wid * 3072;

  // A-frag LDS elem address: row l15, k = r*32 + khi*8 + j ; swizzle bits 3..5 by row
  const int aBase = l15 * U + khi * 8;
  const int aSwz  = (l15 & 7) << 3;

  // staging lane mapping: cl0 = lane>>2 (local col), s = lane&3 (16B k-slot)
  const int cl0 = lane >> 2;
  const int s   = lane & 3;
  const int pos_w = s ^ ((cl0 >> 1) & 3);          // bank-spread slot permute
  const unsigned wo0 = (unsigned)(cl0 * 32 + pos_w * 8);
  const unsigned wo1 = wo0 + 512;
  const int pos_r = khi ^ ((l15 >> 1) & 3);
  const unsigned ro0 = (unsigned)(l15 * 32 + pos_r * 8);
  const unsigned ro1 = ro0 + 512;

  // global elem offsets (chunk 0): PW=512 weights and PW=1024 weights
  const unsigned gA0 = (unsigned)((n0 + cl0) * U) + (unsigned)(s * 8);
  const unsigned gA1 = gA0 + 16u * U;
  const unsigned gB0 = (unsigned)((n0 + cl0) * 2 * U) + (unsigned)(s * 8);
  const unsigned gB1 = gB0 + 16u * 2 * U;

  const int col0 = n0 + l15;
  const int col1 = n0 + 16 + l15;
  const float b1v0 = b1[col0], b1v1 = b1[col1];
  const float b2v0 = b2[col0], b2v1 = b2[col1];

  f32x4 acc[2];

  for (int t = 0; t < SEQ; ++t){
    // ---------- layer 0: o0 = tanh(proj[tok] + s0 @ Wh0) ----------
    acc[0] = 0.0f; acc[1] = 0.0f;
    seg16(Wh0t, gA0, gA1, ring, wo0, wo1, ro0, ro1, st0, aBase, aSwz, acc);
    __syncthreads();                 // everyone done reading st0
    {
      const int rr0 = khi * 4;
#pragma unroll
      for (int j = 0; j < 4; ++j){
        const int rr = rr0 + j;
        const int tk = tokens[(size_t)(rowbase + rr) * SEQ + t];
        const float z0 = acc[0][j] + proj[(size_t)tk * U + col0];
        const float z1 = acc[1][j] + proj[(size_t)tk * U + col1];
        st0[(rr * U + col0) ^ ((rr & 7) << 3)] = f2bf(fast_tanh(z0));
        st0[(rr * U + col1) ^ ((rr & 7) << 3)] = f2bf(fast_tanh(z1));
      }
    }
    __syncthreads();

    // ---------- layer 1: o1 = tanh([o0 | s1] @ [Wx1;Wh1] + b1) ----------
    acc[0] = 0.0f; acc[1] = 0.0f;
    seg16(W1t, gB0, gB1,               ring, wo0, wo1, ro0, ro1, st0, aBase, aSwz, acc);
    seg16(W1t, gB0 + 512, gB1 + 512,   ring, wo0, wo1, ro0, ro1, st1, aBase, aSwz, acc);
    __syncthreads();
    {
      const int rr0 = khi * 4;
#pragma unroll
      for (int j = 0; j < 4; ++j){
        const int rr = rr0 + j;
        st1[(rr * U + col0) ^ ((rr & 7) << 3)] = f2bf(fast_tanh(acc[0][j] + b1v0));
        st1[(rr * U + col1) ^ ((rr & 7) << 3)] = f2bf(fast_tanh(acc[1][j] + b1v1));
      }
    }
    __syncthreads();

    // ---------- layer 2: o2 = tanh([o1 | s2] @ [Wx2;Wh2] + b2) ----------
    acc[0] = 0.0f; acc[1] = 0.0f;
    seg16(W2t, gB0, gB1,               ring, wo0, wo1, ro0, ro1, st1, aBase, aSwz, acc);
    seg16(W2t, gB0 + 512, gB1 + 512,   ring, wo0, wo1, ro0, ro1, st2, aBase, aSwz, acc);
    __syncthreads();
    {
      const int rr0 = khi * 4;
#pragma unroll
      for (int j = 0; j < 4; ++j){
        const int rr = rr0 + j;
        st2[(rr * U + col0) ^ ((rr & 7) << 3)] = f2bf(fast_tanh(acc[0][j] + b2v0));
        st2[(rr * U + col1) ^ ((rr & 7) << 3)] = f2bf(fast_tanh(acc[1][j] + b2v1));
      }
    }
    __syncthreads();
  }

  // ---------- output: sigmoid(s2 @ Wout + bout), one wave per row ----------
  if (wid < RPB){
    const int r = wid;
    float v = 0.0f;
#pragma unroll
    for (int jj = 0; jj < 8; ++jj){
      const int n = lane + jj * 64;
      v += bf2f(st2[(r * U + n) ^ ((r & 7) << 3)]) * Wout[n];
    }
#pragma unroll
    for (int off = 32; off > 0; off >>= 1)
      v += __shfl_down(v, off, 64);
    if (lane == 0)
      out[rowbase + r] = 1.0f / (1.0f + __expf(-(v + bout[0])));
  }
}

extern "C" void kernel_launch(void* const* d_in, const int* in_sizes, int n_in,
                              void* d_out, int out_size, void* d_ws, size_t ws_size,
                              hipStream_t stream){
  (void)in_sizes; (void)n_in; (void)out_size; (void)ws_size;
  const int*   tokens = (const int*)  d_in[0];
  const float* emb  = (const float*)d_in[1];
  const float* Wx0  = (const float*)d_in[2];
  const float* Wh0  = (const float*)d_in[3];
  const float* b0   = (const float*)d_in[4];
  const float* Wx1  = (const float*)d_in[5];
  const float* Wh1  = (const float*)d_in[6];
  const float* b1   = (const float*)d_in[7];
  const float* Wx2  = (const float*)d_in[8];
  const float* Wh2  = (const float*)d_in[9];
  const float* b2   = (const float*)d_in[10];
  const float* Wout = (const float*)d_in[11];
  const float* bout = (const float*)d_in[12];

  char* ws = (char*)d_ws;
  float* proj = (float*)ws;                                   // 10000*512*4  = 20.48 MB
  unsigned short* Wh0t = (unsigned short*)(ws + (size_t)TW * U * 4);
  unsigned short* W1t  = Wh0t + (size_t)U * U;                // [512][1024]
  unsigned short* W2t  = W1t  + (size_t)U * 2 * U;

  proj_kernel<<<TW / 16, 256, 0, stream>>>(emb, Wx0, b0, proj);
  const int tblk = (U * U + 255) / 256;
  transpose_bf16<<<tblk, 256, 0, stream>>>(Wh0, Wh0t, U, U, U,     0);
  transpose_bf16<<<tblk, 256, 0, stream>>>(Wx1, W1t,  U, U, 2 * U, 0);
  transpose_bf16<<<tblk, 256, 0, stream>>>(Wh1, W1t,  U, U, 2 * U, U);
  transpose_bf16<<<tblk, 256, 0, stream>>>(Wx2, W2t,  U, U, 2 * U, 0);
  transpose_bf16<<<tblk, 256, 0, stream>>>(Wh2, W2t,  U, U, 2 * U, U);

  static const int kLds = 147456;   // 48 KiB states + 96 KiB per-wave rings
  (void)hipFuncSetAttribute((const void*)rnn_persist,
                            hipFuncAttributeMaxDynamicSharedMemorySize, kLds);
  rnn_persist<<<NBLK, NTHR, kLds, stream>>>(tokens, proj, Wh0t, W1t, W2t,
                                            b1, b2, Wout, bout, (float*)d_out);
}

// Round 10
// 1795.688 us; speedup vs baseline: 4.4436x; 4.4436x over previous
//
#include <hip/hip_runtime.h>

#define TW    10000
#define EMBD  100
#define SEQ   80
#define U     512
#define BATCH 2048
#define RPB   16
#define NBLK  (BATCH / RPB)   // 128 blocks
#define NTHR  1024            // 16 waves/block

typedef short short8 __attribute__((ext_vector_type(8)));
typedef float f32x4 __attribute__((ext_vector_type(4)));

static __device__ __forceinline__ unsigned short f2bf(float f){
  unsigned int u = __float_as_uint(f);
  u += 0x7fffu + ((u >> 16) & 1u);   // RNE
  return (unsigned short)(u >> 16);
}
static __device__ __forceinline__ float bf2f(unsigned short h){
  return __uint_as_float(((unsigned int)h) << 16);
}
static __device__ __forceinline__ float fast_tanh(float x){
  float e = __expf(2.0f * x);        // inf-safe: saturates to +-1
  return 1.0f - 2.0f / (e + 1.0f);
}

// ---------------- proj[w][n] = b0[n] + sum_e emb[w][e] * Wx0[e][n] ----------------
__global__ void proj_kernel(const float* __restrict__ emb, const float* __restrict__ Wx0,
                            const float* __restrict__ b0, float* __restrict__ proj){
  __shared__ float es[16][EMBD];
  const int w0 = blockIdx.x * 16;
  for (int i = threadIdx.x; i < 16 * EMBD; i += 256)
    es[i / EMBD][i % EMBD] = emb[(size_t)w0 * EMBD + i];
  __syncthreads();
  const int n = threadIdx.x;   // cols n and n+256
  float accA[16], accB[16];
#pragma unroll
  for (int wi = 0; wi < 16; ++wi){ accA[wi] = 0.0f; accB[wi] = 0.0f; }
  for (int e = 0; e < EMBD; ++e){
    const float wv0 = Wx0[(size_t)e * U + n];
    const float wv1 = Wx0[(size_t)e * U + n + 256];
#pragma unroll
    for (int wi = 0; wi < 16; ++wi){
      accA[wi] += es[wi][e] * wv0;
      accB[wi] += es[wi][e] * wv1;
    }
  }
  const float bb0 = b0[n], bb1 = b0[n + 256];
  for (int wi = 0; wi < 16; ++wi){
    proj[(size_t)(w0 + wi) * U + n]       = accA[wi] + bb0;
    proj[(size_t)(w0 + wi) * U + n + 256] = accB[wi] + bb1;
  }
}

// ---- pack src[K][512] f32 into MFMA-fragment order (bf16) ----
// dest elem index for source (k+kOff, n):
//   wid=n>>5, t=(n>>4)&1, c=n&15, kk=k+kOff, ch=kk>>5, khi=(kk>>3)&3, j=kk&7
//   di = wid*NCH*1024 + ch*1024 + t*512 + (khi*16+c)*8 + j
// In-kernel B-load then is: base + wid*NCH*1024 + ch*1024 + t*512 + lane*8
// -> one contiguous 1KB per wave-load (lane*16B), ~8 cache lines vs 64.
__global__ void pack_frag(const float* __restrict__ src, unsigned short* __restrict__ dst,
                          int K, int kOff, int NCH){
  const int idx = blockIdx.x * 256 + threadIdx.x;
  if (idx >= K * 512) return;
  const int k = idx / 512, n = idx % 512;     // reads coalesced over n
  const int wid = n >> 5, t = (n >> 4) & 1, c = n & 15;
  const int kk = k + kOff;
  const int ch = kk >> 5, khi = (kk >> 3) & 3, j = kk & 7;
  const size_t di = (size_t)wid * NCH * 1024 + (size_t)ch * 1024
                  + (size_t)t * 512 + (size_t)(khi * 16 + c) * 8 + j;
  dst[di] = f2bf(src[(size_t)k * 512 + n]);
}

// One GEMM segment over NCH chunks of 32 k. B from packed fragment layout:
// per chunk, two contiguous 1KB loads (lane-ordered). A from swizzled state LDS.
template<int NCH>
static __device__ __forceinline__ void run_segment(
    const unsigned short* __restrict__ Wp,     // this wave's packed base
    unsigned lofs,                             // lane*8 elem offset
    const unsigned short* __restrict__ stA0, const unsigned short* __restrict__ stA1,
    int aBase, int aSwz, f32x4* acc)
{
#pragma unroll 8
  for (int ch = 0; ch < NCH; ++ch){
    const unsigned short* sA = (NCH == 16 || ch < 16) ? stA0 : stA1;
    short8 a  = *reinterpret_cast<const short8*>(&sA[(aBase + (ch & 15) * 32) ^ aSwz]);
    short8 b0 = *reinterpret_cast<const short8*>(Wp + (unsigned)(ch * 1024) + lofs);
    short8 b1 = *reinterpret_cast<const short8*>(Wp + (unsigned)(ch * 1024 + 512) + lofs);
    acc[0] = __builtin_amdgcn_mfma_f32_16x16x32_bf16(a, b0, acc[0], 0, 0, 0);
    acc[1] = __builtin_amdgcn_mfma_f32_16x16x32_bf16(a, b1, acc[1], 0, 0, 0);
  }
}

// ---------------- persistent per-block RNN: 16 rows through all 80 steps ----------------
__global__ __launch_bounds__(NTHR, 4)
void rnn_persist(const int* __restrict__ tokens,
                 const float* __restrict__ proj,
                 const unsigned short* __restrict__ P0,
                 const unsigned short* __restrict__ P1,
                 const unsigned short* __restrict__ P2,
                 const float* __restrict__ b1,
                 const float* __restrict__ b2,
                 const float* __restrict__ Wout,
                 const float* __restrict__ bout,
                 float* __restrict__ out)
{
  __shared__ unsigned short st0[RPB * U];   // 16 KiB each, bf16, XOR-swizzled rows
  __shared__ unsigned short st1[RPB * U];
  __shared__ unsigned short st2[RPB * U];

  const int tid = threadIdx.x;
  for (int i = tid; i < RPB * U; i += NTHR){ st0[i] = 0; st1[i] = 0; st2[i] = 0; }
  __syncthreads();

  const int lane = tid & 63;
  const int wid  = tid >> 6;          // 16 waves, 32 output cols each
  const int l15  = lane & 15;
  const int khi  = lane >> 4;         // 0..3
  const int n0   = wid * 32;
  const int rowbase = blockIdx.x * RPB;

  // A-frag LDS elem address: row l15, k = ch*32 + khi*8 + j ; swizzle bits 3..5 by row
  const int aBase = l15 * U + khi * 8;
  const int aSwz  = (l15 & 7) << 3;

  // packed B bases for this wave + per-lane offset
  const unsigned short* w0p = P0 + (size_t)wid * 16 * 1024;
  const unsigned short* w1p = P1 + (size_t)wid * 32 * 1024;
  const unsigned short* w2p = P2 + (size_t)wid * 32 * 1024;
  const unsigned lofs = (unsigned)lane * 8;

  const int col0 = n0 + l15;
  const int col1 = n0 + 16 + l15;
  const float b1v0 = b1[col0], b1v1 = b1[col1];
  const float b2v0 = b2[col0], b2v1 = b2[col1];

  f32x4 acc[2];

  for (int t = 0; t < SEQ; ++t){
    // ---------- layer 0: o0 = tanh(proj[tok] + s0 @ Wh0) ----------
    acc[0] = 0.0f; acc[1] = 0.0f;
    run_segment<16>(w0p, lofs, st0, st0, aBase, aSwz, acc);
    __syncthreads();                 // everyone done reading st0
    {
      const int rr0 = khi * 4;
#pragma unroll
      for (int j = 0; j < 4; ++j){
        const int rr = rr0 + j;
        const int tk = tokens[(size_t)(rowbase + rr) * SEQ + t];
        const float z0 = acc[0][j] + proj[(size_t)tk * U + col0];
        const float z1 = acc[1][j] + proj[(size_t)tk * U + col1];
        st0[(rr * U + col0) ^ ((rr & 7) << 3)] = f2bf(fast_tanh(z0));
        st0[(rr * U + col1) ^ ((rr & 7) << 3)] = f2bf(fast_tanh(z1));
      }
    }
    __syncthreads();

    // ---------- layer 1: o1 = tanh([o0 | s1] @ [Wx1;Wh1] + b1) ----------
    acc[0] = 0.0f; acc[1] = 0.0f;
    run_segment<32>(w1p, lofs, st0, st1, aBase, aSwz, acc);
    __syncthreads();
    {
      const int rr0 = khi * 4;
#pragma unroll
      for (int j = 0; j < 4; ++j){
        const int rr = rr0 + j;
        st1[(rr * U + col0) ^ ((rr & 7) << 3)] = f2bf(fast_tanh(acc[0][j] + b1v0));
        st1[(rr * U + col1) ^ ((rr & 7) << 3)] = f2bf(fast_tanh(acc[1][j] + b1v1));
      }
    }
    __syncthreads();

    // ---------- layer 2: o2 = tanh([o1 | s2] @ [Wx2;Wh2] + b2) ----------
    acc[0] = 0.0f; acc[1] = 0.0f;
    run_segment<32>(w2p, lofs, st1, st2, aBase, aSwz, acc);
    __syncthreads();
    {
      const int rr0 = khi * 4;
#pragma unroll
      for (int j = 0; j < 4; ++j){
        const int rr = rr0 + j;
        st2[(rr * U + col0) ^ ((rr & 7) << 3)] = f2bf(fast_tanh(acc[0][j] + b2v0));
        st2[(rr * U + col1) ^ ((rr & 7) << 3)] = f2bf(fast_tanh(acc[1][j] + b2v1));
      }
    }
    __syncthreads();
  }

  // ---------- output: sigmoid(s2 @ Wout + bout), one wave per row ----------
  if (wid < RPB){
    const int r = wid;
    float v = 0.0f;
#pragma unroll
    for (int jj = 0; jj < 8; ++jj){
      const int n = lane + jj * 64;
      v += bf2f(st2[(r * U + n) ^ ((r & 7) << 3)]) * Wout[n];
    }
#pragma unroll
    for (int off = 32; off > 0; off >>= 1)
      v += __shfl_down(v, off, 64);
    if (lane == 0)
      out[rowbase + r] = 1.0f / (1.0f + __expf(-(v + bout[0])));
  }
}

extern "C" void kernel_launch(void* const* d_in, const int* in_sizes, int n_in,
                              void* d_out, int out_size, void* d_ws, size_t ws_size,
                              hipStream_t stream){
  (void)in_sizes; (void)n_in; (void)out_size; (void)ws_size;
  const int*   tokens = (const int*)  d_in[0];
  const float* emb  = (const float*)d_in[1];
  const float* Wx0  = (const float*)d_in[2];
  const float* Wh0  = (const float*)d_in[3];
  const float* b0   = (const float*)d_in[4];
  const float* Wx1  = (const float*)d_in[5];
  const float* Wh1  = (const float*)d_in[6];
  const float* b1   = (const float*)d_in[7];
  const float* Wx2  = (const float*)d_in[8];
  const float* Wh2  = (const float*)d_in[9];
  const float* b2   = (const float*)d_in[10];
  const float* Wout = (const float*)d_in[11];
  const float* bout = (const float*)d_in[12];

  char* ws = (char*)d_ws;
  float* proj = (float*)ws;                                   // 10000*512*4  = 20.48 MB
  unsigned short* P0 = (unsigned short*)(ws + (size_t)TW * U * 4);  // 16 waves*16ch*1024 = 512 KB
  unsigned short* P1 = P0 + (size_t)16 * 16 * 1024;                 // 16 waves*32ch*1024 = 1 MB
  unsigned short* P2 = P1 + (size_t)16 * 32 * 1024;                 // 1 MB

  proj_kernel<<<TW / 16, 256, 0, stream>>>(emb, Wx0, b0, proj);
  const int pblk = (U * U + 255) / 256;   // 512*512 elems per source matrix
  pack_frag<<<pblk, 256, 0, stream>>>(Wh0, P0, U, 0, 16);
  pack_frag<<<pblk, 256, 0, stream>>>(Wx1, P1, U, 0, 32);
  pack_frag<<<pblk, 256, 0, stream>>>(Wh1, P1, U, U, 32);
  pack_frag<<<pblk, 256, 0, stream>>>(Wx2, P2, U, 0, 32);
  pack_frag<<<pblk, 256, 0, stream>>>(Wh2, P2, U, U, 32);

  rnn_persist<<<NBLK, NTHR, 0, stream>>>(tokens, proj, P0, P1, P2,
                                         b1, b2, Wout, bout, (float*)d_out);
}

// Round 12
// 1654.302 us; speedup vs baseline: 4.8234x; 1.0855x over previous
//
#include <hip/hip_runtime.h>

#define TW    10000
#define EMBD  100
#define SEQ   80
#define U     512
#define BATCH 2048
#define RPB   16
#define NBLK  (BATCH / RPB)   // 128 blocks
#define NTHR  1024            // 16 waves/block

typedef short short8 __attribute__((ext_vector_type(8)));
typedef float f32x4 __attribute__((ext_vector_type(4)));

static __device__ __forceinline__ unsigned short f2bf(float f){
  unsigned int u = __float_as_uint(f);
  u += 0x7fffu + ((u >> 16) & 1u);   // RNE
  return (unsigned short)(u >> 16);
}
static __device__ __forceinline__ float bf2f(unsigned short h){
  return __uint_as_float(((unsigned int)h) << 16);
}
static __device__ __forceinline__ float fast_tanh(float x){
  float e = __expf(2.0f * x);        // inf-safe: saturates to +-1
  return 1.0f - 2.0f / (e + 1.0f);
}

// ---------------- proj[w][n] = b0[n] + sum_e emb[w][e] * Wx0[e][n] ----------------
__global__ void proj_kernel(const float* __restrict__ emb, const float* __restrict__ Wx0,
                            const float* __restrict__ b0, float* __restrict__ proj){
  __shared__ float es[16][EMBD];
  const int w0 = blockIdx.x * 16;
  for (int i = threadIdx.x; i < 16 * EMBD; i += 256)
    es[i / EMBD][i % EMBD] = emb[(size_t)w0 * EMBD + i];
  __syncthreads();
  const int n = threadIdx.x;   // cols n and n+256
  float accA[16], accB[16];
#pragma unroll
  for (int wi = 0; wi < 16; ++wi){ accA[wi] = 0.0f; accB[wi] = 0.0f; }
  for (int e = 0; e < EMBD; ++e){
    const float wv0 = Wx0[(size_t)e * U + n];
    const float wv1 = Wx0[(size_t)e * U + n + 256];
#pragma unroll
    for (int wi = 0; wi < 16; ++wi){
      accA[wi] += es[wi][e] * wv0;
      accB[wi] += es[wi][e] * wv1;
    }
  }
  const float bb0 = b0[n], bb1 = b0[n + 256];
  for (int wi = 0; wi < 16; ++wi){
    proj[(size_t)(w0 + wi) * U + n]       = accA[wi] + bb0;
    proj[(size_t)(w0 + wi) * U + n + 256] = accB[wi] + bb1;
  }
}

// ---- pack src[K][512] f32 into MFMA-fragment order (bf16) ----
// dest elem index for source (k+kOff, n):
//   wid=n>>5, t=(n>>4)&1, c=n&15, kk=k+kOff, ch=kk>>5, khi=(kk>>3)&3, j=kk&7
//   di = wid*NCH*1024 + ch*1024 + t*512 + (khi*16+c)*8 + j
// In-kernel B-load then is: base + wid*NCH*1024 + ch*1024 + t*512 + lane*8
// -> one contiguous 1KB per wave-load (lane*16B), ~8 cache lines vs 64.
__global__ void pack_frag(const float* __restrict__ src, unsigned short* __restrict__ dst,
                          int K, int kOff, int NCH){
  const int idx = blockIdx.x * 256 + threadIdx.x;
  if (idx >= K * 512) return;
  const int k = idx / 512, n = idx % 512;     // reads coalesced over n
  const int wid = n >> 5, t = (n >> 4) & 1, c = n & 15;
  const int kk = k + kOff;
  const int ch = kk >> 5, khi = (kk >> 3) & 3, j = kk & 7;
  const size_t di = (size_t)wid * NCH * 1024 + (size_t)ch * 1024
                  + (size_t)t * 512 + (size_t)(khi * 16 + c) * 8 + j;
  dst[di] = f2bf(src[(size_t)k * 512 + n]);
}

// One GEMM segment over NCH chunks of 32 k. B from packed fragment layout:
// per chunk, two contiguous 1KB loads (lane-ordered). A from swizzled state LDS.
template<int NCH>
static __device__ __forceinline__ void run_segment(
    const unsigned short* __restrict__ Wp,     // this wave's packed base
    unsigned lofs,                             // lane*8 elem offset
    const unsigned short* __restrict__ stA0, const unsigned short* __restrict__ stA1,
    int aBase, int aSwz, f32x4* acc)
{
#pragma unroll 8
  for (int ch = 0; ch < NCH; ++ch){
    const unsigned short* sA = (NCH == 16 || ch < 16) ? stA0 : stA1;
    short8 a  = *reinterpret_cast<const short8*>(&sA[(aBase + (ch & 15) * 32) ^ aSwz]);
    short8 b0 = *reinterpret_cast<const short8*>(Wp + (unsigned)(ch * 1024) + lofs);
    short8 b1 = *reinterpret_cast<const short8*>(Wp + (unsigned)(ch * 1024 + 512) + lofs);
    acc[0] = __builtin_amdgcn_mfma_f32_16x16x32_bf16(a, b0, acc[0], 0, 0, 0);
    acc[1] = __builtin_amdgcn_mfma_f32_16x16x32_bf16(a, b1, acc[1], 0, 0, 0);
  }
}

// ---------------- persistent per-block RNN: 16 rows through all 80 steps ----------------
// Double-buffered states: seg reads buffer [t&1], epilogue writes [t&1 ^ 1].
// Disjoint read/write buffers -> only 2 visibility barriers per step
// (o0 -> seg1, o1 -> seg2); the t->t+1 boundary is covered by the next
// step's own barriers (dependency distance >= 2 barriers for every pair).
__global__ __launch_bounds__(NTHR, 4)
void rnn_persist(const int* __restrict__ tokens,
                 const float* __restrict__ proj,
                 const unsigned short* __restrict__ P0,
                 const unsigned short* __restrict__ P1,
                 const unsigned short* __restrict__ P2,
                 const float* __restrict__ b1,
                 const float* __restrict__ b2,
                 const float* __restrict__ Wout,
                 const float* __restrict__ bout,
                 float* __restrict__ out)
{
  extern __shared__ unsigned short smem[];   // 6 x 8192 elems = 96 KiB
  // layer L, buffer b: smem + (L*2 + b) * 8192

  const int tid = threadIdx.x;
  for (int i = tid; i < 6 * 8192; i += NTHR) smem[i] = 0;
  __syncthreads();

  const int lane = tid & 63;
  const int wid  = tid >> 6;          // 16 waves, 32 output cols each
  const int l15  = lane & 15;
  const int khi  = lane >> 4;         // 0..3
  const int n0   = wid * 32;
  const int rowbase = blockIdx.x * RPB;

  // A-frag LDS elem address: row l15, k = ch*32 + khi*8 + j ; swizzle bits 3..5 by row
  const int aBase = l15 * U + khi * 8;
  const int aSwz  = (l15 & 7) << 3;

  // packed B bases for this wave + per-lane offset
  const unsigned short* w0p = P0 + (size_t)wid * 16 * 1024;
  const unsigned short* w1p = P1 + (size_t)wid * 32 * 1024;
  const unsigned short* w2p = P2 + (size_t)wid * 32 * 1024;
  const unsigned lofs = (unsigned)lane * 8;

  const int col0 = n0 + l15;
  const int col1 = n0 + 16 + l15;
  const float b1v0 = b1[col0], b1v1 = b1[col1];
  const float b2v0 = b2[col0], b2v1 = b2[col1];
  const int rr0 = khi * 4;

  f32x4 acc[2];

  for (int t = 0; t < SEQ; ++t){
    const int c = t & 1;
    unsigned short* s0r = smem + (0 + c)     * 8192;
    unsigned short* s0w = smem + (0 + (c^1)) * 8192;
    unsigned short* s1r = smem + (2 + c)     * 8192;
    unsigned short* s1w = smem + (2 + (c^1)) * 8192;
    unsigned short* s2r = smem + (4 + c)     * 8192;
    unsigned short* s2w = smem + (4 + (c^1)) * 8192;

    // hoisted token + proj gather (L2+L3 latency hides under seg0's stream)
    const int tk0 = tokens[(size_t)(rowbase + rr0 + 0) * SEQ + t];
    const int tk1 = tokens[(size_t)(rowbase + rr0 + 1) * SEQ + t];
    const int tk2 = tokens[(size_t)(rowbase + rr0 + 2) * SEQ + t];
    const int tk3 = tokens[(size_t)(rowbase + rr0 + 3) * SEQ + t];
    const float pj00 = proj[(size_t)tk0 * U + col0];
    const float pj01 = proj[(size_t)tk1 * U + col0];
    const float pj02 = proj[(size_t)tk2 * U + col0];
    const float pj03 = proj[(size_t)tk3 * U + col0];
    const float pj10 = proj[(size_t)tk0 * U + col1];
    const float pj11 = proj[(size_t)tk1 * U + col1];
    const float pj12 = proj[(size_t)tk2 * U + col1];
    const float pj13 = proj[(size_t)tk3 * U + col1];

    // ---------- layer 0: o0 = tanh(proj[tok] + s0 @ Wh0) ----------
    acc[0] = 0.0f; acc[1] = 0.0f;
    run_segment<16>(w0p, lofs, s0r, s0r, aBase, aSwz, acc);
    // epilogue writes s0w (disjoint from s0r readers) - no barrier needed before
    {
      s0w[((rr0 + 0) * U + col0) ^ (((rr0 + 0) & 7) << 3)] = f2bf(fast_tanh(acc[0][0] + pj00));
      s0w[((rr0 + 1) * U + col0) ^ (((rr0 + 1) & 7) << 3)] = f2bf(fast_tanh(acc[0][1] + pj01));
      s0w[((rr0 + 2) * U + col0) ^ (((rr0 + 2) & 7) << 3)] = f2bf(fast_tanh(acc[0][2] + pj02));
      s0w[((rr0 + 3) * U + col0) ^ (((rr0 + 3) & 7) << 3)] = f2bf(fast_tanh(acc[0][3] + pj03));
      s0w[((rr0 + 0) * U + col1) ^ (((rr0 + 0) & 7) << 3)] = f2bf(fast_tanh(acc[1][0] + pj10));
      s0w[((rr0 + 1) * U + col1) ^ (((rr0 + 1) & 7) << 3)] = f2bf(fast_tanh(acc[1][1] + pj11));
      s0w[((rr0 + 2) * U + col1) ^ (((rr0 + 2) & 7) << 3)] = f2bf(fast_tanh(acc[1][2] + pj12));
      s0w[((rr0 + 3) * U + col1) ^ (((rr0 + 3) & 7) << 3)] = f2bf(fast_tanh(acc[1][3] + pj13));
    }
    __syncthreads();   // B_a: o0 visible

    // ---------- layer 1: o1 = tanh(o0 @ Wx1 + s1 @ Wh1 + b1) ----------
    acc[0] = 0.0f; acc[1] = 0.0f;
    run_segment<32>(w1p, lofs, s0w, s1r, aBase, aSwz, acc);
#pragma unroll
    for (int j = 0; j < 4; ++j){
      const int rr = rr0 + j;
      s1w[(rr * U + col0) ^ ((rr & 7) << 3)] = f2bf(fast_tanh(acc[0][j] + b1v0));
      s1w[(rr * U + col1) ^ ((rr & 7) << 3)] = f2bf(fast_tanh(acc[1][j] + b1v1));
    }
    __syncthreads();   // B_b: o1 visible

    // ---------- layer 2: o2 = tanh(o1 @ Wx2 + s2 @ Wh2 + b2) ----------
    acc[0] = 0.0f; acc[1] = 0.0f;
    run_segment<32>(w2p, lofs, s1w, s2r, aBase, aSwz, acc);
#pragma unroll
    for (int j = 0; j < 4; ++j){
      const int rr = rr0 + j;
      s2w[(rr * U + col0) ^ ((rr & 7) << 3)] = f2bf(fast_tanh(acc[0][j] + b2v0));
      s2w[(rr * U + col1) ^ ((rr & 7) << 3)] = f2bf(fast_tanh(acc[1][j] + b2v1));
    }
    // no barrier: next step's B_a/B_b cover all cross-step dependencies
  }
  __syncthreads();     // final o2 (in buffer (79&1)^1 = 0) visible

  // ---------- output: sigmoid(s2 @ Wout + bout), one wave per row ----------
  {
    const unsigned short* sf = smem + 4 * 8192;   // st2 buffer 0
    const int r = wid;
    float v = 0.0f;
#pragma unroll
    for (int jj = 0; jj < 8; ++jj){
      const int n = lane + jj * 64;
      v += bf2f(sf[(r * U + n) ^ ((r & 7) << 3)]) * Wout[n];
    }
#pragma unroll
    for (int off = 32; off > 0; off >>= 1)
      v += __shfl_down(v, off, 64);
    if (lane == 0)
      out[rowbase + r] = 1.0f / (1.0f + __expf(-(v + bout[0])));
  }
}

extern "C" void kernel_launch(void* const* d_in, const int* in_sizes, int n_in,
                              void* d_out, int out_size, void* d_ws, size_t ws_size,
                              hipStream_t stream){
  (void)in_sizes; (void)n_in; (void)out_size; (void)ws_size;
  const int*   tokens = (const int*)  d_in[0];
  const float* emb  = (const float*)d_in[1];
  const float* Wx0  = (const float*)d_in[2];
  const float* Wh0  = (const float*)d_in[3];
  const float* b0   = (const float*)d_in[4];
  const float* Wx1  = (const float*)d_in[5];
  const float* Wh1  = (const float*)d_in[6];
  const float* b1   = (const float*)d_in[7];
  const float* Wx2  = (const float*)d_in[8];
  const float* Wh2  = (const float*)d_in[9];
  const float* b2   = (const float*)d_in[10];
  const float* Wout = (const float*)d_in[11];
  const float* bout = (const float*)d_in[12];

  char* ws = (char*)d_ws;
  float* proj = (float*)ws;                                   // 20.48 MB
  unsigned short* P0 = (unsigned short*)(ws + (size_t)TW * U * 4);  // 512 KB packed bf16
  unsigned short* P1 = P0 + (size_t)16 * 16 * 1024;                 // 1 MB
  unsigned short* P2 = P1 + (size_t)16 * 32 * 1024;                 // 1 MB

  proj_kernel<<<TW / 16, 256, 0, stream>>>(emb, Wx0, b0, proj);
  const int pblk = (U * U + 255) / 256;   // 512*512 elems per source matrix
  pack_frag<<<pblk, 256, 0, stream>>>(Wh0, P0, U, 0, 16);
  pack_frag<<<pblk, 256, 0, stream>>>(Wx1, P1, U, 0, 32);
  pack_frag<<<pblk, 256, 0, stream>>>(Wh1, P1, U, U, 32);
  pack_frag<<<pblk, 256, 0, stream>>>(Wx2, P2, U, 0, 32);
  pack_frag<<<pblk, 256, 0, stream>>>(Wh2, P2, U, U, 32);

  static const int kLds = 98304;   // 6 x 16 KiB double-buffered states
  (void)hipFuncSetAttribute((const void*)rnn_persist,
                            hipFuncAttributeMaxDynamicSharedMemorySize, kLds);
  rnn_persist<<<NBLK, NTHR, kLds, stream>>>(tokens, proj, P0, P1, P2,
                                            b1, b2, Wout, bout, (float*)d_out);
}